// Round 10
// baseline (255.745 us; speedup 1.0000x reference)
//
#include <hip/hip_runtime.h>
#include <math.h>

// Problem constants: B=512, S=40, V_SC=7000, V_COMPO=1000, K=10
#define PB   512
#define PS   40
#define VSC  7000
#define VC   1000
#define PK   10
#define BK   (PB * PK)          // 5120   sc_labels slab
#define BKS  (PB * PK * PS)     // 204800 each seq slab
#define NROW (2 * PB * PS)      // 40960 compo rows (lr then ul)
#define RPW  8                  // rows per wave (pipelined)

// Any possible tie half-interval: u/2 = ulp(L)/2 <= 2^-22 (L <= log(1000) < 8).
#define NEAR_THR (-2.5e-7f)

// Monotonic float->uint mapping (order-preserving, non-NaN)
__device__ __forceinline__ unsigned int ord_u32(float f) {
    unsigned int u = __float_as_uint(f);
    return (u & 0x80000000u) ? ~u : (u | 0x80000000u);
}

// Each lane holds 16 elements: element m=(j*4+e) is global index (j<<8)+(lane<<2)+e.
__device__ __forceinline__ void load_row16(const float* __restrict__ row, int lane, float* x) {
    const float4* r4 = (const float4*)row;
#pragma unroll
    for (int j = 0; j < 4; ++j) {
        int fi = (j << 6) + lane;
        float4 v;
        if (fi < VC / 4) v = r4[fi];
        else v = make_float4(-INFINITY, -INFINITY, -INFINITY, -INFINITY);
        x[j * 4 + 0] = v.x; x[j * 4 + 1] = v.y; x[j * 4 + 2] = v.z; x[j * 4 + 3] = v.w;
    }
}

// max is exact -> reduction order free
__device__ __forceinline__ float wave_max(const float* x) {
    float bv = -INFINITY;
#pragma unroll
    for (int m = 0; m < 16; ++m) bv = fmaxf(bv, x[m]);
#pragma unroll
    for (int off = 1; off < 64; off <<= 1) bv = fmaxf(bv, __shfl_xor(bv, off, 64));
    return bv;
}

// Deterministic f32 sumexp (order fixed: m ascending, butterfly 1..32). Pad -INF -> +0.
__device__ __forceinline__ float wave_sumexp(const float* x, float xmax) {
    float s = 0.0f;
#pragma unroll
    for (int m = 0; m < 16; ++m) s += expf(x[m] - xmax);
#pragma unroll
    for (int off = 1; off < 64; off <<= 1) s += __shfl_xor(s, off, 64);
    return s;
}

// Per-row fast/slow classification. Arithmetic bitwise-identical to the
// validated round-4/5 code (same lane->element map, ballot order, sum order).
__device__ __forceinline__ void process_row(const float* x, int row, int lane,
                                            unsigned short* __restrict__ ws_t,
                                            unsigned short* __restrict__ ws_pos) {
    const float xmax = wave_max(x);

    // near-max ballots (d <= 0 always; d > NEAR_THR is a superset of any tie set)
    unsigned long long Bn[16];
    int ncnt = 0;
#pragma unroll
    for (int m = 0; m < 16; ++m) Bn[m] = __ballot((x[m] - xmax) > NEAR_THR);
#pragma unroll
    for (int m = 0; m < 16; ++m) ncnt += __popcll(Bn[m]);   // wave-uniform

    if (ncnt == 1) {
        // tie-free row: the single near element is the max itself
        if (lane == 0) {
            int idx = 0;
#pragma unroll
            for (int m = 0; m < 16; ++m) {
                if (Bn[m]) idx = (((m >> 2) << 8)) + ((__ffsll((long long)Bn[m]) - 1) << 2) + (m & 3);
            }
            ws_t[row] = 1;
            ws_pos[row * PK] = (unsigned short)idx;
        }
        return;
    }

    // ---- slow path: exact score-domain ranking (bitwise-validated)
    const float se = wave_sumexp(x, xmax);
    const float L = logf(se);
    const float negL = 0.0f - L;

    int rank_base = 0;
    unsigned long long below = (lane == 0) ? 0ull : ((~0ull) >> (64 - lane));
#pragma unroll
    for (int j = 0; j < 4; ++j) {
        int bit[4];
        unsigned long long Be[4];
#pragma unroll
        for (int e = 0; e < 4; ++e) {
            float scv = (x[j * 4 + e] - xmax) - L;   // bitwise == jax's log_softmax
            bit[e] = (scv == negL) ? 1 : 0;
            Be[e] = __ballot(bit[e]);
        }
        int pre_lane = 0;
#pragma unroll
        for (int e = 0; e < 4; ++e) pre_lane += __popcll(Be[e] & below);
        int within = 0;
#pragma unroll
        for (int e = 0; e < 4; ++e) {
            if (bit[e]) {
                int rk = rank_base + pre_lane + within;
                if (rk < PK) ws_pos[row * PK + rk] =
                    (unsigned short)((j << 8) + (lane << 2) + e);
                ++within;
            }
        }
        int grp = 0;
#pragma unroll
        for (int e = 0; e < 4; ++e) grp += __popcll(Be[e]);
        rank_base += grp;
    }
    if (lane == 0) ws_t[row] = (unsigned short)((rank_base < PK) ? rank_base : PK);
}

// ---------------------------------------------------------------------------
// Kernel 1: exact top-10 indices per row of (512,7000) f32 (raw-logit domain,
// jax.lax.top_k tie semantics). One 256-thread block per row. (validated)
// ---------------------------------------------------------------------------
__global__ __launch_bounds__(256) void topk_sc_kernel(const float* __restrict__ sc,
                                                      int* __restrict__ out) {
    const int b = blockIdx.x;
    const int t = threadIdx.x;
    const float* row = sc + (size_t)b * VSC;

    float v[28];
#pragma unroll
    for (int i = 0; i < 28; ++i) {
        int idx = t + (i << 8);
        v[i] = (idx < VSC) ? row[idx] : -INFINITY;
    }

    __shared__ unsigned long long wk[4];
    __shared__ int winner;

    for (int r = 0; r < PK; ++r) {
        float bv = -INFINITY; int bi = 0;
#pragma unroll
        for (int i = 0; i < 28; ++i) { if (v[i] > bv) { bv = v[i]; bi = i; } }
        int gidx = t + (bi << 8);
        unsigned long long key =
            ((unsigned long long)ord_u32(bv) << 32) |
            (unsigned long long)(0xFFFFFFFFu - (unsigned int)gidx);
#pragma unroll
        for (int off = 1; off < 64; off <<= 1) {
            unsigned long long o = __shfl_xor(key, off, 64);
            if (o > key) key = o;
        }
        if ((t & 63) == 0) wk[t >> 6] = key;
        __syncthreads();
        if (t == 0) {
            unsigned long long k0 = wk[0];
            if (wk[1] > k0) k0 = wk[1];
            if (wk[2] > k0) k0 = wk[2];
            if (wk[3] > k0) k0 = wk[3];
            int widx = (int)(0xFFFFFFFFu - (unsigned int)(k0 & 0xFFFFFFFFu));
            winner = widx;
            out[b * PK + r] = widx;
        }
        __syncthreads();
        int w = winner;
        if ((w & 255) == t) v[w >> 8] = -INFINITY;
    }
}

// ---------------------------------------------------------------------------
// Kernel 2: pipelined rowrank. Each wave owns RPW=8 consecutive rows of one
// tensor (20480 % 8 == 0, so no wave straddles lr/ul). Ping-pong buffer:
// issue row r+1's 4 dwordx4 loads BEFORE processing row r, so loads stream
// continuously for the wave's lifetime (fixes the latency/dispatch-churn
// plateau seen in round 9: 17% BW, VALU 10%). Grid 1280 blocks = fully
// co-resident (5 blocks/CU), zero workgroup churn.
// ---------------------------------------------------------------------------
__global__ __launch_bounds__(256) void rowrank_kernel(const float* __restrict__ lr,
                                                      const float* __restrict__ ul,
                                                      unsigned short* __restrict__ ws_t,
                                                      unsigned short* __restrict__ ws_pos) {
    const int wid  = blockIdx.x * 4 + (threadIdx.x >> 6);   // 0..5119
    const int lane = threadIdx.x & 63;
    const int row0 = wid * RPW;                             // 0..40952
    const int tensor = (row0 >= PB * PS) ? 1 : 0;           // uniform per wave
    const float* base = (tensor ? ul : lr) +
                        (size_t)(row0 - tensor * (PB * PS)) * VC;

    float x[2][16];
    load_row16(base, lane, x[0]);                           // prefetch row 0
#pragma unroll
    for (int r = 0; r < RPW; ++r) {
        if (r + 1 < RPW)
            load_row16(base + (size_t)(r + 1) * VC, lane, x[(r + 1) & 1]);
        process_row(x[r & 1], row0 + r, lane, ws_t, ws_pos);
    }
}

// ---------------------------------------------------------------------------
// Kernel 3: closed-form backward walk. Beam j's token at step i is
// tokpos[i][a_i % t_i] with a_{i-1} = a_i / t_i, a_{S-1} = j.
// One thread per (b, j); ws records are ~1 MB -> L2/L3-resident.
// ---------------------------------------------------------------------------
__global__ __launch_bounds__(256) void build_kernel(const int* __restrict__ struc,
                                                    const unsigned short* __restrict__ ws_t,
                                                    const unsigned short* __restrict__ ws_pos,
                                                    int* __restrict__ out) {
    const int tid = blockIdx.x * 256 + threadIdx.x;   // 0..5119
    if (tid >= PB * PK) return;
    const int b = tid / PK;
    const int j = tid - b * PK;

    int* lrslab = out + BK + (size_t)b * (PK * PS) + (size_t)j * PS;
    int* ulslab = out + BK + BKS + (size_t)b * (PK * PS) + (size_t)j * PS;
    int* res    = out + BK + 2 * BKS + (size_t)b * (PK * PS) + (size_t)j * PS;
    const int st = struc[b];

#pragma unroll
    for (int tensor = 0; tensor < 2; ++tensor) {
        int* slab = tensor ? ulslab : lrslab;
        const int rbase = tensor * (PB * PS) + b * PS;
        int jc = j;
        for (int i = PS - 1; i >= 0; --i) {
            const int t = (int)ws_t[rbase + i];
            int q, c;
            if (t == 1) { q = jc; c = 0; }           // common case: skip u32 divide
            else        { q = jc / t; c = jc - q * t; }
            const int tok = (int)ws_pos[(rbase + i) * PK + c];
            slab[i] = tok;
            if (st == tensor + 1) res[i] = tok;
            jc = q;
        }
    }
    if (st == 0) {
        const int scv = out[b * PK + j];
        for (int i = 0; i < PS; ++i) res[i] = (i == 0) ? scv : 0;
    } else if (st != 1 && st != 2) {
        for (int i = 0; i < PS; ++i) res[i] = 0;
    }
}

extern "C" void kernel_launch(void* const* d_in, const int* in_sizes, int n_in,
                              void* d_out, int out_size, void* d_ws, size_t ws_size,
                              hipStream_t stream) {
    const int*   struc = (const int*)d_in[0];
    const float* sc    = (const float*)d_in[1];
    const float* lr    = (const float*)d_in[2];
    const float* ul    = (const float*)d_in[3];
    int* out = (int*)d_out;

    unsigned short* ws_t   = (unsigned short*)d_ws;   // 40960 * 2B
    unsigned short* ws_pos = ws_t + NROW;             // 409600 * 2B (~900 KB total)

    hipLaunchKernelGGL(topk_sc_kernel, dim3(PB), dim3(256), 0, stream, sc, out);
    hipLaunchKernelGGL(rowrank_kernel, dim3(NROW / (4 * RPW)), dim3(256), 0, stream,
                       lr, ul, ws_t, ws_pos);
    hipLaunchKernelGGL(build_kernel, dim3((PB * PK + 255) / 256), dim3(256), 0, stream,
                       struc, ws_t, ws_pos, out);
}

// Round 11
// 247.208 us; speedup vs baseline: 1.0345x; 1.0345x over previous
//
#include <hip/hip_runtime.h>
#include <math.h>

// Problem constants: B=512, S=40, V_SC=7000, V_COMPO=1000, K=10
#define PB   512
#define PS   40
#define VSC  7000
#define VC   1000
#define PK   10
#define BK   (PB * PK)          // 5120   sc_labels slab
#define BKS  (PB * PK * PS)     // 204800 each seq slab
#define NROW (2 * PB * PS)      // 40960 compo rows (lr then ul)

// Any possible tie half-interval: u/2 = ulp(L)/2 <= 2^-22 (L <= log(1000) < 8).
#define NEAR_THR (-2.5e-7f)

// Monotonic float->uint mapping (order-preserving, non-NaN)
__device__ __forceinline__ unsigned int ord_u32(float f) {
    unsigned int u = __float_as_uint(f);
    return (u & 0x80000000u) ? ~u : (u | 0x80000000u);
}

// Each lane holds 16 elements: element m=(j*4+e) is global index (j<<8)+(lane<<2)+e.
__device__ __forceinline__ void load_row16(const float* __restrict__ row, int lane, float* x) {
    const float4* r4 = (const float4*)row;
#pragma unroll
    for (int j = 0; j < 4; ++j) {
        int fi = (j << 6) + lane;
        float4 v;
        if (fi < VC / 4) v = r4[fi];
        else v = make_float4(-INFINITY, -INFINITY, -INFINITY, -INFINITY);
        x[j * 4 + 0] = v.x; x[j * 4 + 1] = v.y; x[j * 4 + 2] = v.z; x[j * 4 + 3] = v.w;
    }
}

// max is exact -> reduction order free
__device__ __forceinline__ float wave_max(const float* x) {
    float bv = -INFINITY;
#pragma unroll
    for (int m = 0; m < 16; ++m) bv = fmaxf(bv, x[m]);
#pragma unroll
    for (int off = 1; off < 64; off <<= 1) bv = fmaxf(bv, __shfl_xor(bv, off, 64));
    return bv;
}

// Deterministic f32 sumexp (order fixed: m ascending, butterfly 1..32). Pad -INF -> +0.
__device__ __forceinline__ float wave_sumexp(const float* x, float xmax) {
    float s = 0.0f;
#pragma unroll
    for (int m = 0; m < 16; ++m) s += expf(x[m] - xmax);
#pragma unroll
    for (int off = 1; off < 64; off <<= 1) s += __shfl_xor(s, off, 64);
    return s;
}

// Per-row fast/slow classification. Arithmetic bitwise-identical to the
// validated round-4/5 code (same lane->element map, ballot order, sum order).
__device__ __forceinline__ void process_row(const float* x, int row, int lane,
                                            unsigned short* __restrict__ ws_t,
                                            unsigned short* __restrict__ ws_pos) {
    const float xmax = wave_max(x);

    // near-max ballots (d <= 0 always; d > NEAR_THR is a superset of any tie set)
    unsigned long long Bn[16];
    int ncnt = 0;
#pragma unroll
    for (int m = 0; m < 16; ++m) Bn[m] = __ballot((x[m] - xmax) > NEAR_THR);
#pragma unroll
    for (int m = 0; m < 16; ++m) ncnt += __popcll(Bn[m]);   // wave-uniform

    if (ncnt == 1) {
        // tie-free row: the single near element is the max itself
        if (lane == 0) {
            int idx = 0;
#pragma unroll
            for (int m = 0; m < 16; ++m) {
                if (Bn[m]) idx = (((m >> 2) << 8)) + ((__ffsll((long long)Bn[m]) - 1) << 2) + (m & 3);
            }
            ws_t[row] = 1;
            ws_pos[row * PK] = (unsigned short)idx;
        }
        return;
    }

    // ---- slow path: exact score-domain ranking (bitwise-validated)
    const float se = wave_sumexp(x, xmax);
    const float L = logf(se);
    const float negL = 0.0f - L;

    int rank_base = 0;
    unsigned long long below = (lane == 0) ? 0ull : ((~0ull) >> (64 - lane));
#pragma unroll
    for (int j = 0; j < 4; ++j) {
        int bit[4];
        unsigned long long Be[4];
#pragma unroll
        for (int e = 0; e < 4; ++e) {
            float scv = (x[j * 4 + e] - xmax) - L;   // bitwise == jax's log_softmax
            bit[e] = (scv == negL) ? 1 : 0;
            Be[e] = __ballot(bit[e]);
        }
        int pre_lane = 0;
#pragma unroll
        for (int e = 0; e < 4; ++e) pre_lane += __popcll(Be[e] & below);
        int within = 0;
#pragma unroll
        for (int e = 0; e < 4; ++e) {
            if (bit[e]) {
                int rk = rank_base + pre_lane + within;
                if (rk < PK) ws_pos[row * PK + rk] =
                    (unsigned short)((j << 8) + (lane << 2) + e);
                ++within;
            }
        }
        int grp = 0;
#pragma unroll
        for (int e = 0; e < 4; ++e) grp += __popcll(Be[e]);
        rank_base += grp;
    }
    if (lane == 0) ws_t[row] = (unsigned short)((rank_base < PK) ? rank_base : PK);
}

// ---------------------------------------------------------------------------
// Kernel 1: exact top-10 indices per row of (512,7000) f32 (raw-logit domain,
// jax.lax.top_k tie semantics). One 256-thread block per row. (validated)
// ---------------------------------------------------------------------------
__global__ __launch_bounds__(256) void topk_sc_kernel(const float* __restrict__ sc,
                                                      int* __restrict__ out) {
    const int b = blockIdx.x;
    const int t = threadIdx.x;
    const float* row = sc + (size_t)b * VSC;

    float v[28];
#pragma unroll
    for (int i = 0; i < 28; ++i) {
        int idx = t + (i << 8);
        v[i] = (idx < VSC) ? row[idx] : -INFINITY;
    }

    __shared__ unsigned long long wk[4];
    __shared__ int winner;

    for (int r = 0; r < PK; ++r) {
        float bv = -INFINITY; int bi = 0;
#pragma unroll
        for (int i = 0; i < 28; ++i) { if (v[i] > bv) { bv = v[i]; bi = i; } }
        int gidx = t + (bi << 8);
        unsigned long long key =
            ((unsigned long long)ord_u32(bv) << 32) |
            (unsigned long long)(0xFFFFFFFFu - (unsigned int)gidx);
#pragma unroll
        for (int off = 1; off < 64; off <<= 1) {
            unsigned long long o = __shfl_xor(key, off, 64);
            if (o > key) key = o;
        }
        if ((t & 63) == 0) wk[t >> 6] = key;
        __syncthreads();
        if (t == 0) {
            unsigned long long k0 = wk[0];
            if (wk[1] > k0) k0 = wk[1];
            if (wk[2] > k0) k0 = wk[2];
            if (wk[3] > k0) k0 = wk[3];
            int widx = (int)(0xFFFFFFFFu - (unsigned int)(k0 & 0xFFFFFFFFu));
            winner = widx;
            out[b * PK + r] = widx;
        }
        __syncthreads();
        int w = winner;
        if ((w & 255) == t) v[w >> 8] = -INFINITY;
    }
}

// ---------------------------------------------------------------------------
// Kernel 2: deep-MLP rowrank. Each wave owns 4 consecutive rows of one tensor
// (20480 % 4 == 0 -> no wave straddles lr/ul). ALL 16 dwordx4 loads are
// issued back-to-back before any processing (16 KB in flight per wave, 4x
// round-10), then rows are processed in order; the compiler emits counted
// vmcnt waits (12/8/4/0). Named x0..x3 arrays keep indexing compile-time
// (no scratch). Discriminates latency-bound vs on-chip-read-ceiling: if
// latency-bound this roughly halves duration; if ceiling (~2.7 TB/s
// effective) it stays ~61-68 us.
// ---------------------------------------------------------------------------
__global__ __launch_bounds__(256) void rowrank_kernel(const float* __restrict__ lr,
                                                      const float* __restrict__ ul,
                                                      unsigned short* __restrict__ ws_t,
                                                      unsigned short* __restrict__ ws_pos) {
    const int wid  = blockIdx.x * 4 + (threadIdx.x >> 6);   // 0..10239
    const int lane = threadIdx.x & 63;
    const int row0 = wid * 4;                               // 0..40956
    const int tensor = (row0 >= PB * PS) ? 1 : 0;           // uniform per wave
    const float* base = (tensor ? ul : lr) +
                        (size_t)(row0 - tensor * (PB * PS)) * VC;

    float x0[16], x1[16], x2[16], x3[16];
    load_row16(base,                  lane, x0);
    load_row16(base + (size_t)VC,     lane, x1);
    load_row16(base + (size_t)2 * VC, lane, x2);
    load_row16(base + (size_t)3 * VC, lane, x3);

    process_row(x0, row0 + 0, lane, ws_t, ws_pos);
    process_row(x1, row0 + 1, lane, ws_t, ws_pos);
    process_row(x2, row0 + 2, lane, ws_t, ws_pos);
    process_row(x3, row0 + 3, lane, ws_t, ws_pos);
}

// ---------------------------------------------------------------------------
// Kernel 3: closed-form backward walk. Beam j's token at step i is
// tokpos[i][a_i % t_i] with a_{i-1} = a_i / t_i, a_{S-1} = j.
// One thread per (b, j); ws records are ~1 MB -> L2/L3-resident.
// ---------------------------------------------------------------------------
__global__ __launch_bounds__(256) void build_kernel(const int* __restrict__ struc,
                                                    const unsigned short* __restrict__ ws_t,
                                                    const unsigned short* __restrict__ ws_pos,
                                                    int* __restrict__ out) {
    const int tid = blockIdx.x * 256 + threadIdx.x;   // 0..5119
    if (tid >= PB * PK) return;
    const int b = tid / PK;
    const int j = tid - b * PK;

    int* lrslab = out + BK + (size_t)b * (PK * PS) + (size_t)j * PS;
    int* ulslab = out + BK + BKS + (size_t)b * (PK * PS) + (size_t)j * PS;
    int* res    = out + BK + 2 * BKS + (size_t)b * (PK * PS) + (size_t)j * PS;
    const int st = struc[b];

#pragma unroll
    for (int tensor = 0; tensor < 2; ++tensor) {
        int* slab = tensor ? ulslab : lrslab;
        const int rbase = tensor * (PB * PS) + b * PS;
        int jc = j;
        for (int i = PS - 1; i >= 0; --i) {
            const int t = (int)ws_t[rbase + i];
            int q, c;
            if (t == 1) { q = jc; c = 0; }           // common case: skip u32 divide
            else        { q = jc / t; c = jc - q * t; }
            const int tok = (int)ws_pos[(rbase + i) * PK + c];
            slab[i] = tok;
            if (st == tensor + 1) res[i] = tok;
            jc = q;
        }
    }
    if (st == 0) {
        const int scv = out[b * PK + j];
        for (int i = 0; i < PS; ++i) res[i] = (i == 0) ? scv : 0;
    } else if (st != 1 && st != 2) {
        for (int i = 0; i < PS; ++i) res[i] = 0;
    }
}

extern "C" void kernel_launch(void* const* d_in, const int* in_sizes, int n_in,
                              void* d_out, int out_size, void* d_ws, size_t ws_size,
                              hipStream_t stream) {
    const int*   struc = (const int*)d_in[0];
    const float* sc    = (const float*)d_in[1];
    const float* lr    = (const float*)d_in[2];
    const float* ul    = (const float*)d_in[3];
    int* out = (int*)d_out;

    unsigned short* ws_t   = (unsigned short*)d_ws;   // 40960 * 2B
    unsigned short* ws_pos = ws_t + NROW;             // 409600 * 2B (~900 KB total)

    hipLaunchKernelGGL(topk_sc_kernel, dim3(PB), dim3(256), 0, stream, sc, out);
    hipLaunchKernelGGL(rowrank_kernel, dim3(NROW / 16), dim3(256), 0, stream,
                       lr, ul, ws_t, ws_pos);
    hipLaunchKernelGGL(build_kernel, dim3((PB * PK + 255) / 256), dim3(256), 0, stream,
                       struc, ws_t, ws_pos, out);
}